// Round 1
// baseline (271.795 us; speedup 1.0000x reference)
//
#include <hip/hip_runtime.h>
#include <hip/hip_bf16.h>

// GlassBlur: quantize -> blur1 -> floor(u8) -> 49729 sequential neighbor swaps
// per image -> blur2 -> floor -> /255.
//
// Gaussian kernel, sigma=0.4, radius=2, normalized (computed in f64 offline):
//   taps = {w2, w1, w0, w1, w2}
#define KW0 0.91921792f
#define KW1 0.04038762f
#define KW2 3.42560e-6f

#define HH 224
#define WW 224
#define NSW 49729   // 223*223

// ---------------- blur1: f32 [B,C,H,W] -> quantize -> blur -> u8 plane ----------------
__global__ __launch_bounds__(256) void blur1_kernel(const float* __restrict__ x,
                                                    unsigned char* __restrict__ img) {
    const int rb = blockIdx.x;      // 0..27 (8-row blocks)
    const int c  = blockIdx.y;      // 0..2
    const int b  = blockIdx.z;      // 0..63
    const int y0 = rb * 8;
    __shared__ float A[12][WW];
    __shared__ float Bv[8][WW];
    const float* xp = x + ((size_t)(b * 3 + c)) * HH * WW;

    for (int l = threadIdx.x; l < 12 * WW; l += 256) {
        int r = l / WW, xx = l - r * WW;
        int gy = min(max(y0 + r - 2, 0), HH - 1);        // edge pad
        float v = xp[gy * WW + xx];
        v = floorf(fminf(fmaxf(v * 255.0f, 0.0f), 255.0f));  // uint8 quantize
        A[r][xx] = v;
    }
    __syncthreads();
    for (int l = threadIdx.x; l < 8 * WW; l += 256) {
        int r = l / WW, xx = l - r * WW;
        float s = KW2 * A[r][xx] + KW1 * A[r + 1][xx] + KW0 * A[r + 2][xx]
                + KW1 * A[r + 3][xx] + KW2 * A[r + 4][xx];
        Bv[r][xx] = s;
    }
    __syncthreads();
    unsigned char* op = img + ((size_t)(b * 3 + c)) * HH * WW;
    for (int l = threadIdx.x; l < 8 * WW; l += 256) {
        int r = l / WW, xx = l - r * WW;
        int c0 = max(xx - 2, 0), c1 = max(xx - 1, 0);
        int c3 = min(xx + 1, WW - 1), c4 = min(xx + 2, WW - 1);
        float s = KW2 * Bv[r][c0] + KW1 * Bv[r][c1] + KW0 * Bv[r][xx]
                + KW1 * Bv[r][c3] + KW2 * Bv[r][c4];
        op[(y0 + r) * WW + xx] = (unsigned char)floorf(s);   // truncation, matches ref
    }
}

// ---------------- swap: wavefront schedule t = 3u + v, 889 steps ----------------
// u = 223-y (0..222 ascending = program order), v = 223-x (0..222 ascending).
// Same-t swaps have |dv|>=3 -> cell-disjoint. Conflicting swaps always ordered.
__global__ __launch_bounds__(128) void swap_kernel(unsigned char* __restrict__ img,
                                                   const int* __restrict__ deltas) {
    const int b = blockIdx.x, c = blockIdx.y;
    __shared__ __align__(16) unsigned char im[HH * WW];   // 50176 B
    unsigned char* gim = img + ((size_t)(b * 3 + c)) * HH * WW;

    for (int l = threadIdx.x; l < (HH * WW) / 16; l += 128)
        ((int4*)im)[l] = ((const int4*)gim)[l];
    __syncthreads();

    const int2* D = (const int2*)deltas + (size_t)b * NSW;
    const int tid = threadIdx.x;

    // i(u,v) = 223*u + v = 220*u + t  when t = 3u + v.
    auto ld = [&](int t, int2& reg) {
        if (t < 889) {
            int u0 = max(0, (t - 220) / 3);
            int u1 = min(222, t / 3);
            int u = u0 + tid;
            if (u <= u1) reg = D[220 * u + t];
        }
    };
    auto step = [&](int t, int2 d) {
        int u0 = max(0, (t - 220) / 3);
        int u1 = min(222, t / 3);
        int u = u0 + tid;
        if (u <= u1) {
            int v = t - 3 * u;
            int y = 223 - u, x = 223 - v;
            int yp = min(max(y + d.x - 1, 0), HH - 1);
            int xp = min(max(x + d.y - 1, 0), WW - 1);
            int p = y * WW + x;
            int q = yp * WW + xp;
            unsigned char a = im[p], bb = im[q];
            im[p] = bb;
            im[q] = a;
        }
        __syncthreads();
    };

    int2 dA = make_int2(1, 1), dB = make_int2(1, 1);
    ld(0, dA);
    ld(1, dB);
    for (int t = 0; t < 888; t += 2) {
        int2 cur = dA;          // consume (forces wait on prefetched load)
        ld(t + 2, dA);          // prefetch two steps ahead
        step(t, cur);
        int2 cur2 = dB;
        ld(t + 3, dB);
        step(t + 1, cur2);
    }
    {
        int2 cur = dA;
        step(888, cur);
    }

    for (int l = threadIdx.x; l < (HH * WW) / 16; l += 128)
        ((int4*)gim)[l] = ((const int4*)im)[l];
}

// ---------------- blur2: u8 plane -> blur -> floor/clip -> f32 /255 ----------------
__global__ __launch_bounds__(256) void blur2_kernel(const unsigned char* __restrict__ img,
                                                    float* __restrict__ out) {
    const int rb = blockIdx.x;
    const int c  = blockIdx.y;
    const int b  = blockIdx.z;
    const int y0 = rb * 8;
    __shared__ float A[12][WW];
    __shared__ float Bv[8][WW];
    const unsigned char* ip = img + ((size_t)(b * 3 + c)) * HH * WW;

    for (int l = threadIdx.x; l < 12 * WW; l += 256) {
        int r = l / WW, xx = l - r * WW;
        int gy = min(max(y0 + r - 2, 0), HH - 1);
        A[r][xx] = (float)ip[gy * WW + xx];
    }
    __syncthreads();
    for (int l = threadIdx.x; l < 8 * WW; l += 256) {
        int r = l / WW, xx = l - r * WW;
        float s = KW2 * A[r][xx] + KW1 * A[r + 1][xx] + KW0 * A[r + 2][xx]
                + KW1 * A[r + 3][xx] + KW2 * A[r + 4][xx];
        Bv[r][xx] = s;
    }
    __syncthreads();
    float* op = out + ((size_t)(b * 3 + c)) * HH * WW;
    for (int l = threadIdx.x; l < 8 * WW; l += 256) {
        int r = l / WW, xx = l - r * WW;
        int c0 = max(xx - 2, 0), c1 = max(xx - 1, 0);
        int c3 = min(xx + 1, WW - 1), c4 = min(xx + 2, WW - 1);
        float s = KW2 * Bv[r][c0] + KW1 * Bv[r][c1] + KW0 * Bv[r][xx]
                + KW1 * Bv[r][c3] + KW2 * Bv[r][c4];
        s = fminf(fmaxf(s, 0.0f), 255.0f);
        op[(y0 + r) * WW + xx] = floorf(s) / 255.0f;
    }
}

extern "C" void kernel_launch(void* const* d_in, const int* in_sizes, int n_in,
                              void* d_out, int out_size, void* d_ws, size_t ws_size,
                              hipStream_t stream) {
    const float* x      = (const float*)d_in[0];
    const int*   deltas = (const int*)d_in[1];
    float*       out    = (float*)d_out;
    unsigned char* img  = (unsigned char*)d_ws;   // 64*3*224*224 = 9,633,792 B

    dim3 gb(28, 3, 64);
    blur1_kernel<<<gb, 256, 0, stream>>>(x, img);
    swap_kernel<<<dim3(64, 3), 128, 0, stream>>>(img, deltas);
    blur2_kernel<<<gb, 256, 0, stream>>>(img, out);
}

// Round 2
// 265.310 us; speedup vs baseline: 1.0244x; 1.0244x over previous
//
#include <hip/hip_runtime.h>
#include <hip/hip_bf16.h>

// GlassBlur: quantize -> blur1 -> floor(u8) -> 49729 sequential neighbor swaps
// per image -> blur2 -> floor -> /255.
//
// Gaussian kernel, sigma=0.4, radius=2, normalized (f64 offline):
#define KW0 0.91921792f
#define KW1 0.04038762f
#define KW2 3.42560e-6f

#define HH 224
#define WW 224
#define NSW 49729   // 223*223

// ---------------- blur1: f32 [B,C,H,W] -> quantize -> blur -> u8 plane ----------------
__global__ __launch_bounds__(256) void blur1_kernel(const float* __restrict__ x,
                                                    unsigned char* __restrict__ img) {
    const int rb = blockIdx.x;      // 0..27 (8-row blocks)
    const int c  = blockIdx.y;      // 0..2
    const int b  = blockIdx.z;      // 0..63
    const int y0 = rb * 8;
    __shared__ float A[12][WW];
    __shared__ float Bv[8][WW];
    const float* xp = x + ((size_t)(b * 3 + c)) * HH * WW;

    for (int l = threadIdx.x; l < 12 * WW; l += 256) {
        int r = l / WW, xx = l - r * WW;
        int gy = min(max(y0 + r - 2, 0), HH - 1);        // edge pad
        float v = xp[gy * WW + xx];
        v = floorf(fminf(fmaxf(v * 255.0f, 0.0f), 255.0f));  // uint8 quantize
        A[r][xx] = v;
    }
    __syncthreads();
    for (int l = threadIdx.x; l < 8 * WW; l += 256) {
        int r = l / WW, xx = l - r * WW;
        float s = KW2 * A[r][xx] + KW1 * A[r + 1][xx] + KW0 * A[r + 2][xx]
                + KW1 * A[r + 3][xx] + KW2 * A[r + 4][xx];
        Bv[r][xx] = s;
    }
    __syncthreads();
    unsigned char* op = img + ((size_t)(b * 3 + c)) * HH * WW;
    for (int l = threadIdx.x; l < 8 * WW; l += 256) {
        int r = l / WW, xx = l - r * WW;
        int c0 = max(xx - 2, 0), c1 = max(xx - 1, 0);
        int c3 = min(xx + 1, WW - 1), c4 = min(xx + 2, WW - 1);
        float s = KW2 * Bv[r][c0] + KW1 * Bv[r][c1] + KW0 * Bv[r][xx]
                + KW1 * Bv[r][c3] + KW2 * Bv[r][c4];
        op[(y0 + r) * WW + xx] = (unsigned char)floorf(s);   // truncation, matches ref
    }
}

// ---------------- swap: single-wave wavefront t = 4u + v, 1111 steps, 0 barriers --------
// u = 223-y (program order ascending), v = 223-x (ascending within row).
// Same-t swaps: |dv| >= 4 -> touched cells (cols within x+-1) disjoint.
// Conflicting swaps (|du|<=2,|dv|<=2): dt = 4du+dv > 0 -> order preserved.
// Max active lanes per t: ceil(223/4) = 56 <= 64 -> ONE wave, no __syncthreads
// in the main loop (intra-wave LDS ops are in-order; compiler inserts waitcnt).
__global__ __launch_bounds__(64) void swap_kernel(unsigned char* __restrict__ img,
                                                  const int* __restrict__ deltas) {
    // XCD-sharing: image b's 3 channel blocks are blockIdx b, b+64, b+128 -> all
    // same (mod 8) -> same XCD under round-robin dispatch -> delta loads L2-hit.
    const int bid = blockIdx.x;
    const int b = bid & 63, c = bid >> 6;
    __shared__ __align__(16) unsigned char im[HH * WW];   // 50176 B
    unsigned char* gim = img + ((size_t)(b * 3 + c)) * HH * WW;

    const int tid = threadIdx.x;

    for (int l = tid; l < (HH * WW) / 16; l += 64)
        ((int4*)im)[l] = ((const int4*)gim)[l];
    __syncthreads();   // 1-wave: compiles to waitcnt only

    const int2* D = (const int2*)deltas + (size_t)b * NSW;

    // delta index: i = 223*u + v, v = t - 4u  =>  i = 219*u + t
    auto ldf = [&](int t) -> int2 {
        int u0 = max(0, (t - 219) >> 2);      // ceil((t-222)/4), clamped
        int u1 = min(222, t >> 2);
        int u = u0 + tid;
        int2 r = make_int2(1, 1);             // identity delta for inactive lanes
        if (u <= u1) r = D[219 * u + t];
        return r;
    };
    auto stepf = [&](int t, int2 d) {
        int u0 = max(0, (t - 219) >> 2);
        int u1 = min(222, t >> 2);
        int u = u0 + tid;
        if (u <= u1) {
            int v = t - 4 * u;
            int y = 223 - u, x = 223 - v;          // y,x in [1,223]
            int yp = min(y + d.x - 1, HH - 1);     // lower bound >= 0 automatic
            int xp = min(x + d.y - 1, WW - 1);
            int p = y * WW + x;
            int q = yp * WW + xp;
            unsigned char a = im[p], bb = im[q];
            im[p] = bb;
            im[q] = a;                              // p==q -> net identity (matches ref)
        }
    };

    // depth-8 prefetch ring (fully unrolled -> static register indices)
    int2 ring[8];
#pragma unroll
    for (int k = 0; k < 8; ++k) ring[k] = ldf(k);

    for (int tb = 0; tb < 1104; tb += 8) {
#pragma unroll
        for (int k = 0; k < 8; ++k) {
            int2 d = ring[k];
            ring[k] = ldf(tb + k + 8);   // t>1110 self-masks (u0>u1)
            stepf(tb + k, d);
        }
    }
#pragma unroll
    for (int k = 0; k < 7; ++k) stepf(1104 + k, ring[k]);   // t = 1104..1110

    __syncthreads();   // 1-wave: waitcnt only
    for (int l = tid; l < (HH * WW) / 16; l += 64)
        ((int4*)gim)[l] = ((const int4*)im)[l];
}

// ---------------- blur2: u8 plane -> blur -> floor/clip -> f32 /255 ----------------
__global__ __launch_bounds__(256) void blur2_kernel(const unsigned char* __restrict__ img,
                                                    float* __restrict__ out) {
    const int rb = blockIdx.x;
    const int c  = blockIdx.y;
    const int b  = blockIdx.z;
    const int y0 = rb * 8;
    __shared__ float A[12][WW];
    __shared__ float Bv[8][WW];
    const unsigned char* ip = img + ((size_t)(b * 3 + c)) * HH * WW;

    for (int l = threadIdx.x; l < 12 * WW; l += 256) {
        int r = l / WW, xx = l - r * WW;
        int gy = min(max(y0 + r - 2, 0), HH - 1);
        A[r][xx] = (float)ip[gy * WW + xx];
    }
    __syncthreads();
    for (int l = threadIdx.x; l < 8 * WW; l += 256) {
        int r = l / WW, xx = l - r * WW;
        float s = KW2 * A[r][xx] + KW1 * A[r + 1][xx] + KW0 * A[r + 2][xx]
                + KW1 * A[r + 3][xx] + KW2 * A[r + 4][xx];
        Bv[r][xx] = s;
    }
    __syncthreads();
    float* op = out + ((size_t)(b * 3 + c)) * HH * WW;
    for (int l = threadIdx.x; l < 8 * WW; l += 256) {
        int r = l / WW, xx = l - r * WW;
        int c0 = max(xx - 2, 0), c1 = max(xx - 1, 0);
        int c3 = min(xx + 1, WW - 1), c4 = min(xx + 2, WW - 1);
        float s = KW2 * Bv[r][c0] + KW1 * Bv[r][c1] + KW0 * Bv[r][xx]
                + KW1 * Bv[r][c3] + KW2 * Bv[r][c4];
        s = fminf(fmaxf(s, 0.0f), 255.0f);
        op[(y0 + r) * WW + xx] = floorf(s) / 255.0f;
    }
}

extern "C" void kernel_launch(void* const* d_in, const int* in_sizes, int n_in,
                              void* d_out, int out_size, void* d_ws, size_t ws_size,
                              hipStream_t stream) {
    const float* x      = (const float*)d_in[0];
    const int*   deltas = (const int*)d_in[1];
    float*       out    = (float*)d_out;
    unsigned char* img  = (unsigned char*)d_ws;   // 64*3*224*224 = 9,633,792 B

    dim3 gb(28, 3, 64);
    blur1_kernel<<<gb, 256, 0, stream>>>(x, img);
    swap_kernel<<<dim3(192), 64, 0, stream>>>(img, deltas);
    blur2_kernel<<<gb, 256, 0, stream>>>(img, out);
}

// Round 3
// 245.984 us; speedup vs baseline: 1.1049x; 1.0786x over previous
//
#include <hip/hip_runtime.h>
#include <hip/hip_bf16.h>

// GlassBlur via permutation composition.
// final_plane(p) = plane(P(p)),  P = tau_1 o tau_2 o ... o tau_N (first swap leftmost).
// Build: per-row perms (serial depth 223) -> in-block tree to 8-row nodes ->
// 5 global compose passes -> gather-apply (P shared by all 3 channels).
#define KW0 0.91921792f
#define KW1 0.04038762f
#define KW2 3.42560e-6f

#define HH 224
#define WW 224
#define NSW 49729          // 223*223
#define IMG_STRIDE 62720   // u16 entries per image in each perm buffer (28*2240)

// node support rows for chunk covering swap-rows u in [u0, u0+nu)
__device__ __forceinline__ void node_meta(int u0, int nu, int& ys, int& nr) {
    ys = max(0, 223 - u0 - nu);
    int ye = min(223, 224 - u0);
    nr = ye - ys + 1;
}

// ---------------- blur1: f32 -> quantize u8 -> blur -> u8 plane ----------------
__global__ __launch_bounds__(256) void blur1_kernel(const float* __restrict__ x,
                                                    unsigned char* __restrict__ img) {
    const int rb = blockIdx.x, c = blockIdx.y, b = blockIdx.z;
    const int y0 = rb * 8;
    __shared__ float A[12][WW];
    __shared__ float Bv[8][WW];
    const float* xp = x + ((size_t)(b * 3 + c)) * HH * WW;

    for (int l = threadIdx.x; l < 12 * WW; l += 256) {
        int r = l / WW, xx = l - r * WW;
        int gy = min(max(y0 + r - 2, 0), HH - 1);
        float v = xp[gy * WW + xx];
        v = floorf(fminf(fmaxf(v * 255.0f, 0.0f), 255.0f));
        A[r][xx] = v;
    }
    __syncthreads();
    for (int l = threadIdx.x; l < 8 * WW; l += 256) {
        int r = l / WW, xx = l - r * WW;
        Bv[r][xx] = KW2 * A[r][xx] + KW1 * A[r + 1][xx] + KW0 * A[r + 2][xx]
                  + KW1 * A[r + 3][xx] + KW2 * A[r + 4][xx];
    }
    __syncthreads();
    unsigned char* op = img + ((size_t)(b * 3 + c)) * HH * WW;
    for (int l = threadIdx.x; l < 8 * WW; l += 256) {
        int r = l / WW, xx = l - r * WW;
        int c0 = max(xx - 2, 0), c1 = max(xx - 1, 0);
        int c3 = min(xx + 1, WW - 1), c4 = min(xx + 2, WW - 1);
        float s = KW2 * Bv[r][c0] + KW1 * Bv[r][c1] + KW0 * Bv[r][xx]
                + KW1 * Bv[r][c3] + KW2 * Bv[r][c4];
        op[(y0 + r) * WW + xx] = (unsigned char)floorf(s);
    }
}

// ---------------- leaf8: build 8 row-perms serially, compose to one 8-row node --------
// grid (28, 64) = (node j, image b), block 64 (1 wave).
__global__ __launch_bounds__(64) void leaf8_kernel(const int* __restrict__ deltas,
                                                   unsigned short* __restrict__ bufA) {
    const int j = blockIdx.x, b = blockIdx.y;
    const int ubase = j * 8;
    const int nuT = min(8, 223 - ubase);          // 8, or 7 for j=27
    __shared__ unsigned short leaf[8][672];       // 3 rows x 224 per row-perm
    __shared__ unsigned short l1[4][896];         // 4 rows x 224 per 2-row node
    unsigned short* l2 = &leaf[0][0];             // reuse: 2 nodes x (6x224=1344)

    const int tid = threadIdx.x;

    // init leaves to identity (global cell indices)
    for (int e = tid; e < nuT * 672; e += 64) {
        int l = e / 672, o = e - l * 672;
        int ys = 222 - (ubase + l);
        int r = o / 224, cc = o - r * 224;
        leaf[l][o] = (unsigned short)((ys + r) * 224 + cc);
    }
    __syncthreads();

    // serial build: lane l builds row u = ubase+l (223 entry-swaps)
    if (tid < nuT) {
        const int u = ubase + tid;
        const int y = 223 - u;
        const int2* D = (const int2*)deltas + (size_t)b * NSW + (size_t)u * 223;
        unsigned short* Q = leaf[tid];
        int2 ring[8];
#pragma unroll
        for (int k = 0; k < 8; ++k) ring[k] = D[k];
        for (int ib = 0; ib < 224; ib += 8) {
#pragma unroll
            for (int k = 0; k < 8; ++k) {
                int i = ib + k;
                if (i < 223) {
                    int2 d = ring[k];
                    int ip = i + 8;
                    ring[k] = D[ip < 223 ? ip : i];     // harmless refetch at tail
                    int x = 223 - i;
                    int yp = min(y + d.x - 1, HH - 1);  // y>=1 so no lower clamp
                    int xp = min(x + d.y - 1, WW - 1);  // x>=1 so no lower clamp
                    int a  = 224 + x;                    // (y - ys) == 1 always
                    int bq = (yp - (222 - u)) * 224 + xp;
                    unsigned short va = Q[a], vb = Q[bq];
                    Q[a] = vb;
                    Q[bq] = va;
                }
            }
        }
    }
    __syncthreads();

    // L1: pair leaves (2l, 2l+1) -> 4 nodes of span 2
    for (int l = 0; l < 4; ++l) {
        int u0 = ubase + 2 * l;
        int nu = min(2, nuT - 2 * l);
        if (nu <= 0) break;
        int ysO, nrO; node_meta(u0, nu, ysO, nrO);
        int ysA, nrA; node_meta(u0, 1, ysA, nrA);
        bool hasB = (nu == 2);
        int ysB = 0, nrB = 0;
        if (hasB) node_meta(u0 + 1, 1, ysB, nrB);
        for (int e = tid; e < nrO * 224; e += 64) {
            int pr = ysO + e / 224, pc = e % 224;
            unsigned q = pr * 224 + pc;
            if (hasB && pr >= ysB && pr < ysB + nrB)
                q = leaf[2 * l + 1][(pr - ysB) * 224 + pc];
            int qr = q / 224u, qc = q % 224u;
            unsigned r = q;
            if (qr >= ysA && qr < ysA + nrA)
                r = leaf[2 * l][(qr - ysA) * 224 + qc];
            l1[l][e] = (unsigned short)r;
        }
    }
    __syncthreads();

    // L2: pair L1 (2m, 2m+1) -> 2 nodes of span 4 (into reused leaf space)
    for (int m = 0; m < 2; ++m) {
        int u0 = ubase + 4 * m;
        int nu = min(4, nuT - 4 * m);
        if (nu <= 0) break;
        int ysO, nrO; node_meta(u0, nu, ysO, nrO);
        int nuA = min(2, nu);
        int ysA, nrA; node_meta(u0, nuA, ysA, nrA);
        int nuB = nu - 2;
        bool hasB = nuB > 0;
        int ysB = 0, nrB = 0;
        if (hasB) node_meta(u0 + 2, nuB, ysB, nrB);
        for (int e = tid; e < nrO * 224; e += 64) {
            int pr = ysO + e / 224, pc = e % 224;
            unsigned q = pr * 224 + pc;
            if (hasB && pr >= ysB && pr < ysB + nrB)
                q = l1[2 * m + 1][(pr - ysB) * 224 + pc];
            int qr = q / 224u, qc = q % 224u;
            unsigned r = q;
            if (qr >= ysA && qr < ysA + nrA)
                r = l1[2 * m][(qr - ysA) * 224 + qc];
            l2[m * 1344 + e] = (unsigned short)r;
        }
    }
    __syncthreads();

    // L3: compose the two span-4 nodes -> span-8 node, write to global bufA
    {
        int u0 = ubase, nu = nuT;
        int ysO, nrO; node_meta(u0, nu, ysO, nrO);
        int nuA = min(4, nu);
        int ysA, nrA; node_meta(u0, nuA, ysA, nrA);
        int nuB = nu - 4;
        bool hasB = nuB > 0;
        int ysB = 0, nrB = 0;
        if (hasB) node_meta(u0 + 4, nuB, ysB, nrB);
        unsigned short* R = bufA + (size_t)b * IMG_STRIDE + (size_t)j * 2240;
        for (int e = tid; e < nrO * 224; e += 64) {
            int pr = ysO + e / 224, pc = e % 224;
            unsigned q = pr * 224 + pc;
            if (hasB && pr >= ysB && pr < ysB + nrB)
                q = l2[1344 + (pr - ysB) * 224 + pc];
            int qr = q / 224u, qc = q % 224u;
            unsigned r = q;
            if (qr >= ysA && qr < ysA + nrA)
                r = l2[(qr - ysA) * 224 + qc];
            R[e] = (unsigned short)r;
        }
    }
}

// ---------------- global pairwise compose: span -> 2*span ----------------
// grid (64, nOut), block 256. R(p) = A(B(p)); A = node 2j (earlier swaps).
__global__ __launch_bounds__(256) void compose_kernel(const unsigned short* __restrict__ in,
                                                      unsigned short* __restrict__ out,
                                                      int spanIn, int slotIn, int slotOut) {
    const int b = blockIdx.x;
    const int jo = blockIdx.y;
    const int u0 = jo * 2 * spanIn;
    const int nu = min(2 * spanIn, 223 - u0);
    int ysO, nrO; node_meta(u0, nu, ysO, nrO);
    const int nuA = min(spanIn, 223 - u0);
    int ysA, nrA; node_meta(u0, nuA, ysA, nrA);
    const int u0B = u0 + spanIn;
    const int nuB = min(spanIn, 223 - u0B);
    const bool hasB = nuB > 0;
    int ysB = 0, nrB = 0;
    if (hasB) node_meta(u0B, nuB, ysB, nrB);

    const unsigned short* A  = in + (size_t)b * IMG_STRIDE + (size_t)(2 * jo) * slotIn;
    const unsigned short* Bn = in + (size_t)b * IMG_STRIDE + (size_t)(2 * jo + 1) * slotIn;
    unsigned short* R = out + (size_t)b * IMG_STRIDE + (size_t)jo * slotOut;

    for (int e = threadIdx.x; e < nrO * 224; e += 256) {
        int pr = ysO + e / 224, pc = e % 224;
        unsigned q = pr * 224 + pc;
        if (hasB && pr >= ysB && pr < ysB + nrB)
            q = Bn[(pr - ysB) * 224 + pc];
        int qr = q / 224u, qc = q % 224u;
        unsigned r = q;
        if (qr >= ysA && qr < ysA + nrA)
            r = A[(qr - ysA) * 224 + qc];
        R[e] = (unsigned short)r;
    }
}

// ---------------- apply: plane(p) <- plane(P(p)), in-place via LDS ----------------
__global__ __launch_bounds__(256) void apply_kernel(unsigned char* __restrict__ img,
                                                    const unsigned short* __restrict__ P) {
    const int plane = blockIdx.x;          // 0..191
    const int b = plane / 3;
    __shared__ __align__(16) unsigned char im[HH * WW];
    unsigned char* g = img + (size_t)plane * (HH * WW);
    for (int l = threadIdx.x; l < (HH * WW) / 16; l += 256)
        ((int4*)im)[l] = ((const int4*)g)[l];
    __syncthreads();
    const unsigned short* Pp = P + (size_t)b * IMG_STRIDE;   // root: identity layout
    for (int t = threadIdx.x; t < (HH * WW) / 8; t += 256) {
        uint4 pe = ((const uint4*)Pp)[t];                     // 8 perm entries
        unsigned e0 = pe.x & 0xffffu, e1 = pe.x >> 16;
        unsigned e2 = pe.y & 0xffffu, e3 = pe.y >> 16;
        unsigned e4 = pe.z & 0xffffu, e5 = pe.z >> 16;
        unsigned e6 = pe.w & 0xffffu, e7 = pe.w >> 16;
        unsigned lo = (unsigned)im[e0] | ((unsigned)im[e1] << 8)
                    | ((unsigned)im[e2] << 16) | ((unsigned)im[e3] << 24);
        unsigned hi = (unsigned)im[e4] | ((unsigned)im[e5] << 8)
                    | ((unsigned)im[e6] << 16) | ((unsigned)im[e7] << 24);
        ((uint2*)g)[t] = make_uint2(lo, hi);
    }
}

// ---------------- blur2: u8 plane -> blur -> floor/clip -> f32 /255 ----------------
__global__ __launch_bounds__(256) void blur2_kernel(const unsigned char* __restrict__ img,
                                                    float* __restrict__ out) {
    const int rb = blockIdx.x, c = blockIdx.y, b = blockIdx.z;
    const int y0 = rb * 8;
    __shared__ float A[12][WW];
    __shared__ float Bv[8][WW];
    const unsigned char* ip = img + ((size_t)(b * 3 + c)) * HH * WW;

    for (int l = threadIdx.x; l < 12 * WW; l += 256) {
        int r = l / WW, xx = l - r * WW;
        int gy = min(max(y0 + r - 2, 0), HH - 1);
        A[r][xx] = (float)ip[gy * WW + xx];
    }
    __syncthreads();
    for (int l = threadIdx.x; l < 8 * WW; l += 256) {
        int r = l / WW, xx = l - r * WW;
        Bv[r][xx] = KW2 * A[r][xx] + KW1 * A[r + 1][xx] + KW0 * A[r + 2][xx]
                  + KW1 * A[r + 3][xx] + KW2 * A[r + 4][xx];
    }
    __syncthreads();
    float* op = out + ((size_t)(b * 3 + c)) * HH * WW;
    for (int l = threadIdx.x; l < 8 * WW; l += 256) {
        int r = l / WW, xx = l - r * WW;
        int c0 = max(xx - 2, 0), c1 = max(xx - 1, 0);
        int c3 = min(xx + 1, WW - 1), c4 = min(xx + 2, WW - 1);
        float s = KW2 * Bv[r][c0] + KW1 * Bv[r][c1] + KW0 * Bv[r][xx]
                + KW1 * Bv[r][c3] + KW2 * Bv[r][c4];
        s = fminf(fmaxf(s, 0.0f), 255.0f);
        op[(y0 + r) * WW + xx] = floorf(s) / 255.0f;
    }
}

extern "C" void kernel_launch(void* const* d_in, const int* in_sizes, int n_in,
                              void* d_out, int out_size, void* d_ws, size_t ws_size,
                              hipStream_t stream) {
    const float* x      = (const float*)d_in[0];
    const int*   deltas = (const int*)d_in[1];
    float*       out    = (float*)d_out;
    unsigned char* img  = (unsigned char*)d_ws;                 // 9,633,792 B

    // perm ping-pong buffers live in d_out (u16), overwritten by blur2 at the end
    unsigned short* bufA = (unsigned short*)d_out;              // 64*62720*2 = 8.03 MB
    unsigned short* bufB = bufA + (size_t)64 * IMG_STRIDE;      // next 8.03 MB

    dim3 gb(28, 3, 64);
    blur1_kernel<<<gb, 256, 0, stream>>>(x, img);

    leaf8_kernel<<<dim3(28, 64), 64, 0, stream>>>(deltas, bufA);        // span 8 -> bufA
    compose_kernel<<<dim3(64, 14), 256, 0, stream>>>(bufA, bufB, 8,   2240,  4032);
    compose_kernel<<<dim3(64, 7),  256, 0, stream>>>(bufB, bufA, 16,  4032,  7616);
    compose_kernel<<<dim3(64, 4),  256, 0, stream>>>(bufA, bufB, 32,  7616,  14784);
    compose_kernel<<<dim3(64, 2),  256, 0, stream>>>(bufB, bufA, 64,  14784, 29120);
    compose_kernel<<<dim3(64, 1),  256, 0, stream>>>(bufA, bufB, 128, 29120, 50176);

    apply_kernel<<<dim3(192), 256, 0, stream>>>(img, bufB);     // P shared across channels
    blur2_kernel<<<gb, 256, 0, stream>>>(img, out);
}

// Round 4
// 183.264 us; speedup vs baseline: 1.4831x; 1.3422x over previous
//
#include <hip/hip_runtime.h>
#include <hip/hip_bf16.h>

// GlassBlur via permutation composition.
// final_plane(p) = plane(P(p)),  P = tau_1 o tau_2 o ... o tau_N (first swap leftmost),
// so for chunks A (earlier) and B (later):  P(p) = A(B(p)).
// Tree: 28 span-8 leaf nodes -> C1: 7 span-32 -> C2: span-128 + span-95 -> C3: root P.
// In every compose, the LAST chunk's lookup is coalesced (indexed by p); inner chunks
// are staged in LDS so their random gathers are ~9cy instead of ~400cy L2.
#define KW0 0.91921792f
#define KW1 0.04038762f
#define KW2 3.42560e-6f

#define HH 224
#define WW 224
#define NSW 49729          // 223*223
#define IMG_STRIDE 62720   // u16 entries per image per perm buffer
#define SLOT8 2240         // 10 rows x 224
#define SLOT32 7616        // 34 rows x 224
#define N128_ENT 28896     // 129 rows x 224 (span-128 node, rows 95..223)
#define N95_OFF 28896      // span-95 node offset in bufA (rows 0..96, 97x224)

// support rows for chunk covering swap-rows u in [u0, u0+nu)
__device__ __forceinline__ void node_meta(int u0, int nu, int& ys, int& nr) {
    ys = max(0, 223 - u0 - nu);
    int ye = min(223, 224 - u0);
    nr = ye - ys + 1;
}

// ---------------- blur1: f32 -> quantize u8 -> blur -> u8 plane ----------------
__global__ __launch_bounds__(256) void blur1_kernel(const float* __restrict__ x,
                                                    unsigned char* __restrict__ img) {
    const int rb = blockIdx.x, c = blockIdx.y, b = blockIdx.z;
    const int y0 = rb * 8;
    __shared__ float A[12][WW];
    __shared__ float Bv[8][WW];
    const float* xp = x + ((size_t)(b * 3 + c)) * HH * WW;

    for (int l = threadIdx.x; l < 12 * WW; l += 256) {
        int r = l / WW, xx = l - r * WW;
        int gy = min(max(y0 + r - 2, 0), HH - 1);
        float v = xp[gy * WW + xx];
        v = floorf(fminf(fmaxf(v * 255.0f, 0.0f), 255.0f));
        A[r][xx] = v;
    }
    __syncthreads();
    for (int l = threadIdx.x; l < 8 * WW; l += 256) {
        int r = l / WW, xx = l - r * WW;
        Bv[r][xx] = KW2 * A[r][xx] + KW1 * A[r + 1][xx] + KW0 * A[r + 2][xx]
                  + KW1 * A[r + 3][xx] + KW2 * A[r + 4][xx];
    }
    __syncthreads();
    unsigned char* op = img + ((size_t)(b * 3 + c)) * HH * WW;
    for (int l = threadIdx.x; l < 8 * WW; l += 256) {
        int r = l / WW, xx = l - r * WW;
        int c0 = max(xx - 2, 0), c1 = max(xx - 1, 0);
        int c3 = min(xx + 1, WW - 1), c4 = min(xx + 2, WW - 1);
        float s = KW2 * Bv[r][c0] + KW1 * Bv[r][c1] + KW0 * Bv[r][xx]
                + KW1 * Bv[r][c3] + KW2 * Bv[r][c4];
        op[(y0 + r) * WW + xx] = (unsigned char)floorf(s);
    }
}

// ---------------- leaf8: build 8 row-perms serially, compose to one 8-row node --------
__global__ __launch_bounds__(64) void leaf8_kernel(const int* __restrict__ deltas,
                                                   unsigned short* __restrict__ bufA) {
    const int j = blockIdx.x, b = blockIdx.y;
    const int ubase = j * 8;
    const int nuT = min(8, 223 - ubase);
    __shared__ unsigned short leaf[8][672];
    __shared__ unsigned short l1[4][896];
    unsigned short* l2 = &leaf[0][0];

    const int tid = threadIdx.x;

    for (int e = tid; e < nuT * 672; e += 64) {
        int l = e / 672, o = e - l * 672;
        int ys = 222 - (ubase + l);
        int r = o / 224, cc = o - r * 224;
        leaf[l][o] = (unsigned short)((ys + r) * 224 + cc);
    }
    __syncthreads();

    if (tid < nuT) {
        const int u = ubase + tid;
        const int y = 223 - u;
        const int2* D = (const int2*)deltas + (size_t)b * NSW + (size_t)u * 223;
        unsigned short* Q = leaf[tid];
        int2 ring[8];
#pragma unroll
        for (int k = 0; k < 8; ++k) ring[k] = D[k];
        for (int ib = 0; ib < 224; ib += 8) {
#pragma unroll
            for (int k = 0; k < 8; ++k) {
                int i = ib + k;
                if (i < 223) {
                    int2 d = ring[k];
                    int ip = i + 8;
                    ring[k] = D[ip < 223 ? ip : i];
                    int x = 223 - i;
                    int yp = min(y + d.x - 1, HH - 1);
                    int xp = min(x + d.y - 1, WW - 1);
                    int a  = 224 + x;
                    int bq = (yp - (222 - u)) * 224 + xp;
                    unsigned short va = Q[a], vb = Q[bq];
                    Q[a] = vb;
                    Q[bq] = va;
                }
            }
        }
    }
    __syncthreads();

    for (int l = 0; l < 4; ++l) {
        int u0 = ubase + 2 * l;
        int nu = min(2, nuT - 2 * l);
        if (nu <= 0) break;
        int ysO, nrO; node_meta(u0, nu, ysO, nrO);
        int ysA, nrA; node_meta(u0, 1, ysA, nrA);
        bool hasB = (nu == 2);
        int ysB = 0, nrB = 0;
        if (hasB) node_meta(u0 + 1, 1, ysB, nrB);
        for (int e = tid; e < nrO * 224; e += 64) {
            int pr = ysO + e / 224, pc = e % 224;
            unsigned q = pr * 224 + pc;
            if (hasB && pr >= ysB && pr < ysB + nrB)
                q = leaf[2 * l + 1][(pr - ysB) * 224 + pc];
            int qr = q / 224u, qc = q % 224u;
            unsigned r = q;
            if (qr >= ysA && qr < ysA + nrA)
                r = leaf[2 * l][(qr - ysA) * 224 + qc];
            l1[l][e] = (unsigned short)r;
        }
    }
    __syncthreads();

    for (int m = 0; m < 2; ++m) {
        int u0 = ubase + 4 * m;
        int nu = min(4, nuT - 4 * m);
        if (nu <= 0) break;
        int ysO, nrO; node_meta(u0, nu, ysO, nrO);
        int nuA = min(2, nu);
        int ysA, nrA; node_meta(u0, nuA, ysA, nrA);
        int nuB = nu - 2;
        bool hasB = nuB > 0;
        int ysB = 0, nrB = 0;
        if (hasB) node_meta(u0 + 2, nuB, ysB, nrB);
        for (int e = tid; e < nrO * 224; e += 64) {
            int pr = ysO + e / 224, pc = e % 224;
            unsigned q = pr * 224 + pc;
            if (hasB && pr >= ysB && pr < ysB + nrB)
                q = l1[2 * m + 1][(pr - ysB) * 224 + pc];
            int qr = q / 224u, qc = q % 224u;
            unsigned r = q;
            if (qr >= ysA && qr < ysA + nrA)
                r = l1[2 * m][(qr - ysA) * 224 + qc];
            l2[m * 1344 + e] = (unsigned short)r;
        }
    }
    __syncthreads();

    {
        int u0 = ubase, nu = nuT;
        int ysO, nrO; node_meta(u0, nu, ysO, nrO);
        int nuA = min(4, nu);
        int ysA, nrA; node_meta(u0, nuA, ysA, nrA);
        int nuB = nu - 4;
        bool hasB = nuB > 0;
        int ysB = 0, nrB = 0;
        if (hasB) node_meta(u0 + 4, nuB, ysB, nrB);
        unsigned short* R = bufA + (size_t)b * IMG_STRIDE + (size_t)j * SLOT8;
        for (int e = tid; e < nrO * 224; e += 64) {
            int pr = ysO + e / 224, pc = e % 224;
            unsigned q = pr * 224 + pc;
            if (hasB && pr >= ysB && pr < ysB + nrB)
                q = l2[1344 + (pr - ysB) * 224 + pc];
            int qr = q / 224u, qc = q % 224u;
            unsigned r = q;
            if (qr >= ysA && qr < ysA + nrA)
                r = l2[(qr - ysA) * 224 + qc];
            R[e] = (unsigned short)r;
        }
    }
}

// ---------------- C1: compose 4 span-8 nodes -> span-32 node ----------------
// grid (64, 7, 2). Inner nodes A,B,C staged in LDS; D read coalesced.
__global__ __launch_bounds__(256) void compose32_kernel(const unsigned short* __restrict__ in,
                                                        unsigned short* __restrict__ out) {
    const int b = blockIdx.x, jo = blockIdx.y, sp = blockIdx.z;
    const int u0 = jo * 32;
    const int nu = min(32, 223 - u0);
    int ysO, nrO; node_meta(u0, nu, ysO, nrO);
    __shared__ unsigned short sm[3][SLOT8];
    int ysS[3], nrS[3];
    const unsigned short* base = in + (size_t)b * IMG_STRIDE;
#pragma unroll
    for (int m = 0; m < 3; ++m) {
        int ju = 4 * jo + m;
        int nuu = min(8, 223 - 8 * ju);
        node_meta(8 * ju, nuu, ysS[m], nrS[m]);
        for (int l = threadIdx.x; l < nrS[m] * 224; l += 256)
            sm[m][l] = base[ju * SLOT8 + l];
    }
    int ysD, nrD;
    {
        int ju = 4 * jo + 3;
        int nuu = min(8, 223 - 8 * ju);
        node_meta(8 * ju, nuu, ysD, nrD);
    }
    const unsigned short* D = base + (size_t)(4 * jo + 3) * SLOT8;
    __syncthreads();
    unsigned short* R = out + (size_t)b * IMG_STRIDE + (size_t)jo * SLOT32;
    const int cnt = nrO * 224;
    const int half = (cnt + 1) / 2;
    const int e0 = sp * half, e1 = min(cnt, e0 + half);
    for (int e = e0 + threadIdx.x; e < e1; e += 256) {
        int pr = ysO + e / 224, pc = e % 224;
        unsigned q = pr * 224 + pc;
        int dr = pr - ysD;
        if (dr >= 0 && dr < nrD) q = D[dr * 224 + pc];
#pragma unroll
        for (int m = 2; m >= 0; --m) {
            int qr = q / 224u, qc = q % 224u;
            int rr = qr - ysS[m];
            if (rr >= 0 && rr < nrS[m]) q = sm[m][rr * 224 + qc];
        }
        R[e] = (unsigned short)q;
    }
}

// ---------------- C2: compose span-32 nodes -> span-128 (jo=0) / span-95 (jo=1) --------
// grid (64, 2, 4). jo=0: inner 0..3 (stage 0,1,2; 3 coalesced) -> rows 95..223.
//                  jo=1: inner 4,5,6 (stage 4,5; 6 coalesced)  -> rows 0..96.
__global__ __launch_bounds__(256) void compose128_kernel(const unsigned short* __restrict__ in,
                                                         unsigned short* __restrict__ out) {
    const int b = blockIdx.x, jo = blockIdx.y, sp = blockIdx.z;
    const int nStage = jo == 0 ? 3 : 2;
    const int jD = jo == 0 ? 3 : 6;
    const int u0 = jo * 128;
    const int nu = min(128, 223 - u0);
    int ysO, nrO; node_meta(u0, nu, ysO, nrO);
    __shared__ unsigned short sm[3][SLOT32];   // 45.7 KB
    int ysS[3], nrS[3];
    const unsigned short* base = in + (size_t)b * IMG_STRIDE;
#pragma unroll
    for (int m = 0; m < 3; ++m) {
        ysS[m] = 0; nrS[m] = 0;
        if (m < nStage) {
            int ju = 4 * jo + m;
            int nuu = min(32, 223 - 32 * ju);
            node_meta(32 * ju, nuu, ysS[m], nrS[m]);
            for (int l = threadIdx.x; l < nrS[m] * 224; l += 256)
                sm[m][l] = base[ju * SLOT32 + l];
        }
    }
    int ysD, nrD;
    {
        int nuu = min(32, 223 - 32 * jD);
        node_meta(32 * jD, nuu, ysD, nrD);
    }
    const unsigned short* D = base + (size_t)jD * SLOT32;
    __syncthreads();
    unsigned short* R = out + (size_t)b * IMG_STRIDE + (jo ? N95_OFF : 0);
    const int cnt = nrO * 224;
    const int chunk = (cnt + 3) / 4;
    const int e0 = sp * chunk, e1 = min(cnt, e0 + chunk);
    for (int e = e0 + threadIdx.x; e < e1; e += 256) {
        int pr = ysO + e / 224, pc = e % 224;
        unsigned q = pr * 224 + pc;
        int dr = pr - ysD;
        if (dr >= 0 && dr < nrD) q = D[dr * 224 + pc];
#pragma unroll
        for (int m = 2; m >= 0; --m) {
            if (m < nStage) {
                int qr = q / 224u, qc = q % 224u;
                int rr = qr - ysS[m];
                if (rr >= 0 && rr < nrS[m]) q = sm[m][rr * 224 + qc];
            }
        }
        R[e] = (unsigned short)q;
    }
}

// ---------------- C3: root P = A(span-128, rows 95..223) o B(span-95, rows 0..96) ------
// grid (64, 4). A staged in LDS (57.8KB); B read coalesced; P written coalesced.
__global__ __launch_bounds__(256) void compose_final_kernel(const unsigned short* __restrict__ in,
                                                            unsigned short* __restrict__ out) {
    const int b = blockIdx.x, sp = blockIdx.y;
    __shared__ unsigned short A[N128_ENT];     // 57792 B
    const unsigned short* base = in + (size_t)b * IMG_STRIDE;
    for (int l = threadIdx.x; l < N128_ENT / 8; l += 256)
        ((uint4*)A)[l] = ((const uint4*)base)[l];
    const unsigned short* Bn = base + N95_OFF;
    __syncthreads();
    unsigned short* R = out + (size_t)b * IMG_STRIDE;
    const int e0 = sp * 12544;
    for (int e = e0 + threadIdx.x; e < e0 + 12544; e += 256) {
        int pr = e / 224;
        unsigned q = (unsigned)e;
        if (pr < 97) q = Bn[e];
        unsigned qr = q / 224u;
        if (qr >= 95) q = A[q - 95 * 224];
        R[e] = (unsigned short)q;
    }
}

// ---------------- apply: plane(p) <- plane(P(p)), in-place via LDS ----------------
__global__ __launch_bounds__(256) void apply_kernel(unsigned char* __restrict__ img,
                                                    const unsigned short* __restrict__ P) {
    const int plane = blockIdx.x;
    const int b = plane / 3;
    __shared__ __align__(16) unsigned char im[HH * WW];
    unsigned char* g = img + (size_t)plane * (HH * WW);
    for (int l = threadIdx.x; l < (HH * WW) / 16; l += 256)
        ((int4*)im)[l] = ((const int4*)g)[l];
    __syncthreads();
    const unsigned short* Pp = P + (size_t)b * IMG_STRIDE;
    for (int t = threadIdx.x; t < (HH * WW) / 8; t += 256) {
        uint4 pe = ((const uint4*)Pp)[t];
        unsigned e0 = pe.x & 0xffffu, e1 = pe.x >> 16;
        unsigned e2 = pe.y & 0xffffu, e3 = pe.y >> 16;
        unsigned e4 = pe.z & 0xffffu, e5 = pe.z >> 16;
        unsigned e6 = pe.w & 0xffffu, e7 = pe.w >> 16;
        unsigned lo = (unsigned)im[e0] | ((unsigned)im[e1] << 8)
                    | ((unsigned)im[e2] << 16) | ((unsigned)im[e3] << 24);
        unsigned hi = (unsigned)im[e4] | ((unsigned)im[e5] << 8)
                    | ((unsigned)im[e6] << 16) | ((unsigned)im[e7] << 24);
        ((uint2*)g)[t] = make_uint2(lo, hi);
    }
}

// ---------------- blur2: u8 plane -> blur -> floor/clip -> f32 /255 ----------------
__global__ __launch_bounds__(256) void blur2_kernel(const unsigned char* __restrict__ img,
                                                    float* __restrict__ out) {
    const int rb = blockIdx.x, c = blockIdx.y, b = blockIdx.z;
    const int y0 = rb * 8;
    __shared__ float A[12][WW];
    __shared__ float Bv[8][WW];
    const unsigned char* ip = img + ((size_t)(b * 3 + c)) * HH * WW;

    for (int l = threadIdx.x; l < 12 * WW; l += 256) {
        int r = l / WW, xx = l - r * WW;
        int gy = min(max(y0 + r - 2, 0), HH - 1);
        A[r][xx] = (float)ip[gy * WW + xx];
    }
    __syncthreads();
    for (int l = threadIdx.x; l < 8 * WW; l += 256) {
        int r = l / WW, xx = l - r * WW;
        Bv[r][xx] = KW2 * A[r][xx] + KW1 * A[r + 1][xx] + KW0 * A[r + 2][xx]
                  + KW1 * A[r + 3][xx] + KW2 * A[r + 4][xx];
    }
    __syncthreads();
    float* op = out + ((size_t)(b * 3 + c)) * HH * WW;
    for (int l = threadIdx.x; l < 8 * WW; l += 256) {
        int r = l / WW, xx = l - r * WW;
        int c0 = max(xx - 2, 0), c1 = max(xx - 1, 0);
        int c3 = min(xx + 1, WW - 1), c4 = min(xx + 2, WW - 1);
        float s = KW2 * Bv[r][c0] + KW1 * Bv[r][c1] + KW0 * Bv[r][xx]
                + KW1 * Bv[r][c3] + KW2 * Bv[r][c4];
        s = fminf(fmaxf(s, 0.0f), 255.0f);
        op[(y0 + r) * WW + xx] = floorf(s) / 255.0f;
    }
}

extern "C" void kernel_launch(void* const* d_in, const int* in_sizes, int n_in,
                              void* d_out, int out_size, void* d_ws, size_t ws_size,
                              hipStream_t stream) {
    const float* x      = (const float*)d_in[0];
    const int*   deltas = (const int*)d_in[1];
    float*       out    = (float*)d_out;
    unsigned char* img  = (unsigned char*)d_ws;                 // 9,633,792 B

    unsigned short* bufA = (unsigned short*)d_out;              // 8.03 MB
    unsigned short* bufB = bufA + (size_t)64 * IMG_STRIDE;      // 8.03 MB

    dim3 gb(28, 3, 64);
    blur1_kernel<<<gb, 256, 0, stream>>>(x, img);

    leaf8_kernel<<<dim3(28, 64), 64, 0, stream>>>(deltas, bufA);          // span-8 -> bufA
    compose32_kernel<<<dim3(64, 7, 2), 256, 0, stream>>>(bufA, bufB);     // span-32 -> bufB
    compose128_kernel<<<dim3(64, 2, 4), 256, 0, stream>>>(bufB, bufA);    // 128/95 -> bufA
    compose_final_kernel<<<dim3(64, 4), 256, 0, stream>>>(bufA, bufB);    // root P -> bufB

    apply_kernel<<<dim3(192), 256, 0, stream>>>(img, bufB);
    blur2_kernel<<<gb, 256, 0, stream>>>(img, out);
}

// Round 5
// 164.357 us; speedup vs baseline: 1.6537x; 1.1150x over previous
//
#include <hip/hip_runtime.h>
#include <hip/hip_bf16.h>

// GlassBlur via permutation composition.
// final_plane(p) = plane(P(p)),  P = tau_1 o tau_2 o ... o tau_N (first swap leftmost),
// so for chunks A (earlier) and B (later):  P(p) = A(B(p)).
// leaf32: per-row perms built in a 3x3 REGISTER window (VALU-only serial chain),
// in-block tree -> span-32 nodes. Then compose128 -> final root P -> apply -> blur2.
#define KW0 0.91921792f
#define KW1 0.04038762f
#define KW2 3.42560e-6f

#define HH 224
#define WW 224
#define NSW 49729          // 223*223
#define IMG_STRIDE 62720   // u16 entries per image per perm buffer
#define SLOT32 7616        // 34 rows x 224
#define N128_ENT 28896     // 129 rows x 224 (span-128 node, rows 95..223)
#define N95_OFF 28896      // span-95 node offset (rows 0..96)

// support rows for chunk covering swap-rows u in [u0, u0+nu)
__device__ __forceinline__ void node_meta(int u0, int nu, int& ys, int& nr) {
    ys = max(0, 223 - u0 - nu);
    int ye = min(223, 224 - u0);
    nr = ye - ys + 1;
}

// ---------------- blur1: f32 -> quantize u8 -> blur -> u8 plane ----------------
__global__ __launch_bounds__(256) void blur1_kernel(const float* __restrict__ x,
                                                    unsigned char* __restrict__ img) {
    const int rb = blockIdx.x, c = blockIdx.y, b = blockIdx.z;
    const int y0 = rb * 8;
    __shared__ float A[12][WW];
    __shared__ float Bv[8][WW];
    const float* xp = x + ((size_t)(b * 3 + c)) * HH * WW;

    for (int l = threadIdx.x; l < 12 * WW; l += 256) {
        int r = l / WW, xx = l - r * WW;
        int gy = min(max(y0 + r - 2, 0), HH - 1);
        float v = xp[gy * WW + xx];
        v = floorf(fminf(fmaxf(v * 255.0f, 0.0f), 255.0f));
        A[r][xx] = v;
    }
    __syncthreads();
    for (int l = threadIdx.x; l < 8 * WW; l += 256) {
        int r = l / WW, xx = l - r * WW;
        Bv[r][xx] = KW2 * A[r][xx] + KW1 * A[r + 1][xx] + KW0 * A[r + 2][xx]
                  + KW1 * A[r + 3][xx] + KW2 * A[r + 4][xx];
    }
    __syncthreads();
    unsigned char* op = img + ((size_t)(b * 3 + c)) * HH * WW;
    for (int l = threadIdx.x; l < 8 * WW; l += 256) {
        int r = l / WW, xx = l - r * WW;
        int c0 = max(xx - 2, 0), c1 = max(xx - 1, 0);
        int c3 = min(xx + 1, WW - 1), c4 = min(xx + 2, WW - 1);
        float s = KW2 * Bv[r][c0] + KW1 * Bv[r][c1] + KW0 * Bv[r][xx]
                + KW1 * Bv[r][c3] + KW2 * Bv[r][c4];
        op[(y0 + r) * WW + xx] = (unsigned char)floorf(s);
    }
}

// ---------------- leaf32: register-window row perms + in-block tree to span-32 --------
// grid (7, 64) = (node j: rows u in [32j,32j+32), image b), 256 threads.
// Build: lane l (<32) builds row u=32j+l. State = 3x3 register window over
// rows {y-1,y,y+1} x cols {x-1,x,x+1}; col x+1 retires (3 ds_write_b16) after
// each swap; cols < x-1 are identity. Swap = 9-way cndmask select, no LDS reads.
__global__ __launch_bounds__(256) void leaf32_kernel(const int* __restrict__ deltas,
                                                     unsigned short* __restrict__ outB) {
    const int j = blockIdx.x;
    const int b = blockIdx.y;
    const int u0blk = j * 32;
    const int uEnd = min(u0blk + 32, 223);
    const int nuT = uEnd - u0blk;

    __shared__ unsigned short leafS[32 * 676];   // 43264 B (3x224 rows + pad, stride 676)
    __shared__ unsigned short auxS[4 * 2240];    // 17920 B (4 span-8 nodes)

    const int tid = threadIdx.x;
    const int u = u0blk + tid;

    if (tid < 32 && u < 223) {
        const int y = 223 - u;
        const bool ytop = (y == 223);
        const int2* Drow = (const int2*)deltas + (size_t)b * NSW + (size_t)u * 223;
        unsigned short* Lf = &leafS[tid * 676];
        const int b0r = (y - 1) * 224, b1r = y * 224, b2r = (y + 1) * 224;

        // window: w{row}{colrole}; init for x=223 -> cols 222,223,224(junk, never selected)
        unsigned w00 = b0r + 222, w01 = b0r + 223, w02 = b0r + 224;
        unsigned w10 = b1r + 222, w11 = b1r + 223, w12 = b1r + 224;
        unsigned w20 = b2r + 222, w21 = b2r + 223, w22 = b2r + 224;

        int2 ring[24];
#pragma unroll
        for (int k = 0; k < 24; ++k) ring[k] = Drow[k];

        // peel i=0 (x=223): roles (L,M,R)=(0,1,2); pc clamp; no emission
        {
            int2 d_ = ring[0];
            ring[0] = Drow[24];
            const int dy_ = d_.x - 1, dx_ = d_.y - 1;
            const int pr_ = (ytop && dy_ == 1) ? 1 : dy_ + 1;
            const int pc_ = (dx_ == 1) ? 1 : dx_ + 1;
            const int idx_ = pr_ * 3 + pc_;
            unsigned v_ = w00;
            v_ = idx_ == 1 ? w01 : v_;  v_ = idx_ == 2 ? w02 : v_;
            v_ = idx_ == 3 ? w10 : v_;  v_ = idx_ == 4 ? w11 : v_;
            v_ = idx_ == 5 ? w12 : v_;  v_ = idx_ == 6 ? w20 : v_;
            v_ = idx_ == 7 ? w21 : v_;  v_ = idx_ == 8 ? w22 : v_;
            const unsigned c_ = w11;
            w00 = idx_ == 0 ? c_ : w00;
            w01 = idx_ == 1 ? c_ : w01;
            w02 = idx_ == 2 ? c_ : w02;
            w10 = idx_ == 3 ? c_ : w10;
            w12 = idx_ == 5 ? c_ : w12;
            w20 = idx_ == 6 ? c_ : w20;
            w21 = idx_ == 7 ? c_ : w21;
            w22 = idx_ == 8 ? c_ : w22;
            w11 = v_;
            // reinit role R (suffix 2) to incoming col 221
            w02 = (unsigned)(b0r + 221); w12 = (unsigned)(b1r + 221); w22 = (unsigned)(b2r + 221);
        }

#define GB_RS(KK) (((KK) + 1) % 24)
#define GB_STEP(KK, CA, CB, CC) {                                         \
            const int i_ = ibase + (KK);                                  \
            const int x_ = 223 - i_;                                      \
            int2 d_ = ring[GB_RS(KK)];                                    \
            int ip_ = i_ + 24; ip_ = ip_ <= 222 ? ip_ : 222;              \
            ring[GB_RS(KK)] = Drow[ip_];                                  \
            const int dy_ = d_.x - 1, dx_ = d_.y - 1;                     \
            const int pr_ = (ytop && dy_ == 1) ? 1 : dy_ + 1;             \
            const int pc_ = dx_ + 1;                                      \
            const int idx_ = pr_ * 3 + pc_;                               \
            unsigned v_ = w0##CA;                                         \
            v_ = idx_ == 1 ? w0##CB : v_;  v_ = idx_ == 2 ? w0##CC : v_;  \
            v_ = idx_ == 3 ? w1##CA : v_;  v_ = idx_ == 4 ? w1##CB : v_;  \
            v_ = idx_ == 5 ? w1##CC : v_;  v_ = idx_ == 6 ? w2##CA : v_;  \
            v_ = idx_ == 7 ? w2##CB : v_;  v_ = idx_ == 8 ? w2##CC : v_;  \
            const unsigned c_ = w1##CB;                                   \
            w0##CA = idx_ == 0 ? c_ : w0##CA;                             \
            w0##CB = idx_ == 1 ? c_ : w0##CB;                             \
            w0##CC = idx_ == 2 ? c_ : w0##CC;                             \
            w1##CA = idx_ == 3 ? c_ : w1##CA;                             \
            w1##CC = idx_ == 5 ? c_ : w1##CC;                             \
            w2##CA = idx_ == 6 ? c_ : w2##CA;                             \
            w2##CB = idx_ == 7 ? c_ : w2##CB;                             \
            w2##CC = idx_ == 8 ? c_ : w2##CC;                             \
            w1##CB = v_;                                                  \
            Lf[x_ + 1]   = (unsigned short)w0##CC;                        \
            Lf[x_ + 225] = (unsigned short)w1##CC;                        \
            Lf[x_ + 449] = (unsigned short)w2##CC;                        \
            w0##CC = (unsigned)(b0r + (x_ - 2));                          \
            w1##CC = (unsigned)(b1r + (x_ - 2));                          \
            w2##CC = (unsigned)(b2r + (x_ - 2));                          \
        }
#define GB_TRIPLE(K0) GB_STEP((K0), 2, 0, 1) GB_STEP((K0)+1, 1, 2, 0) GB_STEP((K0)+2, 0, 1, 2)

        for (int blk = 0; blk < 9; ++blk) {          // i = 1..216
            const int ibase = 1 + 24 * blk;
            GB_TRIPLE(0)  GB_TRIPLE(3)  GB_TRIPLE(6)  GB_TRIPLE(9)
            GB_TRIPLE(12) GB_TRIPLE(15) GB_TRIPLE(18) GB_TRIPLE(21)
        }
        {                                            // i = 217..222
            const int ibase = 217;
            GB_TRIPLE(0) GB_TRIPLE(3)
        }
        // final emit: col 1 (role M = suffix 1), col 0 (role L = suffix 0)
        Lf[1] = (unsigned short)w01; Lf[225] = (unsigned short)w11; Lf[449] = (unsigned short)w21;
        Lf[0] = (unsigned short)w00; Lf[224] = (unsigned short)w10; Lf[448] = (unsigned short)w20;
#undef GB_TRIPLE
#undef GB_STEP
#undef GB_RS
    }
    __syncthreads();

    // P1: chase 8 leaves (latest->earliest) -> span-8 node in auxS, 2-way ILP
    for (int k = 0; k < 4; ++k) {
        const int u0 = u0blk + 8 * k;
        const int nu = min(8, uEnd - u0);
        int ysO, nrO; node_meta(u0, nu, ysO, nrO);
        unsigned short* R = &auxS[k * 2240];
        const int cnt = nrO * 224;
        for (int e = tid; e < cnt; e += 512) {
            const int e2 = e + 256;
            const bool has2 = e2 < cnt;
            const int pr1 = ysO + e / 224, pc1 = e % 224;
            unsigned q1 = (unsigned)(pr1 * 224 + pc1);
            const int pr2 = ysO + e2 / 224, pc2 = e2 % 224;
            unsigned q2 = (unsigned)(pr2 * 224 + pc2);
            for (int m = nu - 1; m >= 0; --m) {
                const int lbase = (8 * k + m) * 676;
                const int ys = 222 - (u0 + m);
                { const int qr = (int)(q1 / 224u), qc = (int)q1 - qr * 224, off = qr - ys;
                  if (off >= 0 && off < 3) q1 = leafS[lbase + off * 224 + qc]; }
                { const int qr = (int)(q2 / 224u), qc = (int)q2 - qr * 224, off = qr - ys;
                  if (off >= 0 && off < 3) q2 = leafS[lbase + off * 224 + qc]; }
            }
            R[e] = (unsigned short)q1;
            if (has2) R[e2] = (unsigned short)q2;
        }
    }
    __syncthreads();

    // P2: chase 4 span-8 nodes -> span-32 node, write global (bufB layout)
    {
        int ysO, nrO; node_meta(u0blk, nuT, ysO, nrO);
        unsigned short* R = outB + (size_t)b * IMG_STRIDE + (size_t)j * SLOT32;
        int ysA[4], nrA[4];
#pragma unroll
        for (int m = 0; m < 4; ++m) {
            const int u0 = u0blk + 8 * m;
            const int nu = min(8, uEnd - u0);
            node_meta(u0, nu, ysA[m], nrA[m]);
        }
        const int cnt = nrO * 224;
        for (int e = tid; e < cnt; e += 512) {
            const int e2 = e + 256;
            const bool has2 = e2 < cnt;
            const int pr1 = ysO + e / 224, pc1 = e % 224;
            unsigned q1 = (unsigned)(pr1 * 224 + pc1);
            const int pr2 = ysO + e2 / 224, pc2 = e2 % 224;
            unsigned q2 = (unsigned)(pr2 * 224 + pc2);
#pragma unroll
            for (int m = 3; m >= 0; --m) {
                { const int qr = (int)(q1 / 224u), qc = (int)q1 - qr * 224, off = qr - ysA[m];
                  if (off >= 0 && off < nrA[m]) q1 = auxS[m * 2240 + off * 224 + qc]; }
                { const int qr = (int)(q2 / 224u), qc = (int)q2 - qr * 224, off = qr - ysA[m];
                  if (off >= 0 && off < nrA[m]) q2 = auxS[m * 2240 + off * 224 + qc]; }
            }
            R[e] = (unsigned short)q1;
            if (has2) R[e2] = (unsigned short)q2;
        }
    }
}

// ---------------- C2: compose span-32 nodes -> span-128 (jo=0) / span-95 (jo=1) --------
__global__ __launch_bounds__(256) void compose128_kernel(const unsigned short* __restrict__ in,
                                                         unsigned short* __restrict__ out) {
    const int b = blockIdx.x, jo = blockIdx.y, sp = blockIdx.z;
    const int nStage = jo == 0 ? 3 : 2;
    const int jD = jo == 0 ? 3 : 6;
    const int u0 = jo * 128;
    const int nu = min(128, 223 - u0);
    int ysO, nrO; node_meta(u0, nu, ysO, nrO);
    __shared__ unsigned short sm[3][SLOT32];   // 45.7 KB
    int ysS[3], nrS[3];
    const unsigned short* base = in + (size_t)b * IMG_STRIDE;
#pragma unroll
    for (int m = 0; m < 3; ++m) {
        ysS[m] = 0; nrS[m] = 0;
        if (m < nStage) {
            int ju = 4 * jo + m;
            int nuu = min(32, 223 - 32 * ju);
            node_meta(32 * ju, nuu, ysS[m], nrS[m]);
            for (int l = threadIdx.x; l < nrS[m] * 224; l += 256)
                sm[m][l] = base[ju * SLOT32 + l];
        }
    }
    int ysD, nrD;
    {
        int nuu = min(32, 223 - 32 * jD);
        node_meta(32 * jD, nuu, ysD, nrD);
    }
    const unsigned short* D = base + (size_t)jD * SLOT32;
    __syncthreads();
    unsigned short* R = out + (size_t)b * IMG_STRIDE + (jo ? N95_OFF : 0);
    const int cnt = nrO * 224;
    const int chunk = (cnt + 3) / 4;
    const int e0 = sp * chunk, e1 = min(cnt, e0 + chunk);
    for (int e = e0 + threadIdx.x; e < e1; e += 256) {
        int pr = ysO + e / 224, pc = e % 224;
        unsigned q = pr * 224 + pc;
        int dr = pr - ysD;
        if (dr >= 0 && dr < nrD) q = D[dr * 224 + pc];
#pragma unroll
        for (int m = 2; m >= 0; --m) {
            if (m < nStage) {
                int qr = q / 224u, qc = q % 224u;
                int rr = qr - ysS[m];
                if (rr >= 0 && rr < nrS[m]) q = sm[m][rr * 224 + qc];
            }
        }
        R[e] = (unsigned short)q;
    }
}

// ---------------- C3: root P = A(span-128, rows 95..223) o B(span-95, rows 0..96) ------
__global__ __launch_bounds__(256) void compose_final_kernel(const unsigned short* __restrict__ in,
                                                            unsigned short* __restrict__ out) {
    const int b = blockIdx.x, sp = blockIdx.y;
    __shared__ unsigned short A[N128_ENT];     // 57792 B
    const unsigned short* base = in + (size_t)b * IMG_STRIDE;
    for (int l = threadIdx.x; l < N128_ENT / 8; l += 256)
        ((uint4*)A)[l] = ((const uint4*)base)[l];
    const unsigned short* Bn = base + N95_OFF;
    __syncthreads();
    unsigned short* R = out + (size_t)b * IMG_STRIDE;
    const int e0 = sp * 12544;
    for (int e = e0 + threadIdx.x; e < e0 + 12544; e += 256) {
        int pr = e / 224;
        unsigned q = (unsigned)e;
        if (pr < 97) q = Bn[e];
        unsigned qr = q / 224u;
        if (qr >= 95) q = A[q - 95 * 224];
        R[e] = (unsigned short)q;
    }
}

// ---------------- apply: plane(p) <- plane(P(p)), in-place via LDS ----------------
__global__ __launch_bounds__(256) void apply_kernel(unsigned char* __restrict__ img,
                                                    const unsigned short* __restrict__ P) {
    const int plane = blockIdx.x;
    const int b = plane / 3;
    __shared__ __align__(16) unsigned char im[HH * WW];
    unsigned char* g = img + (size_t)plane * (HH * WW);
    for (int l = threadIdx.x; l < (HH * WW) / 16; l += 256)
        ((int4*)im)[l] = ((const int4*)g)[l];
    __syncthreads();
    const unsigned short* Pp = P + (size_t)b * IMG_STRIDE;
    for (int t = threadIdx.x; t < (HH * WW) / 8; t += 256) {
        uint4 pe = ((const uint4*)Pp)[t];
        unsigned e0 = pe.x & 0xffffu, e1 = pe.x >> 16;
        unsigned e2 = pe.y & 0xffffu, e3 = pe.y >> 16;
        unsigned e4 = pe.z & 0xffffu, e5 = pe.z >> 16;
        unsigned e6 = pe.w & 0xffffu, e7 = pe.w >> 16;
        unsigned lo = (unsigned)im[e0] | ((unsigned)im[e1] << 8)
                    | ((unsigned)im[e2] << 16) | ((unsigned)im[e3] << 24);
        unsigned hi = (unsigned)im[e4] | ((unsigned)im[e5] << 8)
                    | ((unsigned)im[e6] << 16) | ((unsigned)im[e7] << 24);
        ((uint2*)g)[t] = make_uint2(lo, hi);
    }
}

// ---------------- blur2: u8 plane -> blur -> floor/clip -> f32 /255 ----------------
__global__ __launch_bounds__(256) void blur2_kernel(const unsigned char* __restrict__ img,
                                                    float* __restrict__ out) {
    const int rb = blockIdx.x, c = blockIdx.y, b = blockIdx.z;
    const int y0 = rb * 8;
    __shared__ float A[12][WW];
    __shared__ float Bv[8][WW];
    const unsigned char* ip = img + ((size_t)(b * 3 + c)) * HH * WW;

    for (int l = threadIdx.x; l < 12 * WW; l += 256) {
        int r = l / WW, xx = l - r * WW;
        int gy = min(max(y0 + r - 2, 0), HH - 1);
        A[r][xx] = (float)ip[gy * WW + xx];
    }
    __syncthreads();
    for (int l = threadIdx.x; l < 8 * WW; l += 256) {
        int r = l / WW, xx = l - r * WW;
        Bv[r][xx] = KW2 * A[r][xx] + KW1 * A[r + 1][xx] + KW0 * A[r + 2][xx]
                  + KW1 * A[r + 3][xx] + KW2 * A[r + 4][xx];
    }
    __syncthreads();
    float* op = out + ((size_t)(b * 3 + c)) * HH * WW;
    for (int l = threadIdx.x; l < 8 * WW; l += 256) {
        int r = l / WW, xx = l - r * WW;
        int c0 = max(xx - 2, 0), c1 = max(xx - 1, 0);
        int c3 = min(xx + 1, WW - 1), c4 = min(xx + 2, WW - 1);
        float s = KW2 * Bv[r][c0] + KW1 * Bv[r][c1] + KW0 * Bv[r][xx]
                + KW1 * Bv[r][c3] + KW2 * Bv[r][c4];
        s = fminf(fmaxf(s, 0.0f), 255.0f);
        op[(y0 + r) * WW + xx] = floorf(s) / 255.0f;
    }
}

extern "C" void kernel_launch(void* const* d_in, const int* in_sizes, int n_in,
                              void* d_out, int out_size, void* d_ws, size_t ws_size,
                              hipStream_t stream) {
    const float* x      = (const float*)d_in[0];
    const int*   deltas = (const int*)d_in[1];
    float*       out    = (float*)d_out;
    unsigned char* img  = (unsigned char*)d_ws;                 // 9,633,792 B

    unsigned short* bufA = (unsigned short*)d_out;              // 8.03 MB
    unsigned short* bufB = bufA + (size_t)64 * IMG_STRIDE;      // 8.03 MB

    dim3 gb(28, 3, 64);
    blur1_kernel<<<gb, 256, 0, stream>>>(x, img);

    leaf32_kernel<<<dim3(7, 64), 256, 0, stream>>>(deltas, bufB);         // span-32 -> bufB
    compose128_kernel<<<dim3(64, 2, 4), 256, 0, stream>>>(bufB, bufA);    // 128/95 -> bufA
    compose_final_kernel<<<dim3(64, 4), 256, 0, stream>>>(bufA, bufB);    // root P -> bufB

    apply_kernel<<<dim3(192), 256, 0, stream>>>(img, bufB);
    blur2_kernel<<<gb, 256, 0, stream>>>(img, out);
}